// Round 8
// baseline (26367.719 us; speedup 1.0000x reference)
//
#include <hip/hip_runtime.h>
#include <hip/hip_bf16.h>
#include <stdint.h>

#define T_LEN 16384
#define HDIM 512
#define G4 2048
#define CLAMP_MAXV 49688.0f

// workspace layout (bytes)
#define XG_OFF    0ull
#define HS_OFF    134217728ull   // 16384*2048*4
#define INTER_OFF 167772160ull   // + 16384*512*4  (ctrl+probe alias the first
                                 //  4.2KB of inter: dead until after the scan)
#define HREC_OFF  176160768ull   // + 16384*128*4
#define BSUM_OFF  176168960ull   // + 8192
#define WS_NEED   176177152ull

#define SCAN_BLOCKS 32
// s_getreg encoding: id=20 (HW_REG_XCC_ID, gfx940+), offset 0, size 32
#define XCC_ID_ENC (20 | (0 << 6) | ((32 - 1) << 11))

// sc0 (L1-bypass) 8B ops. Loads cache in the local XCD L2 -> only coherent
// when all participants share ONE physical L2. That property is VERIFIED by
// the two-round probe below; sc0 is never used on live data without a pass.
__device__ __forceinline__ uint64_t l2_load_u64(const uint64_t* p) {
    uint64_t v;
    asm volatile("global_load_dwordx2 %0, %1, off sc0\n\ts_waitcnt vmcnt(0)"
                 : "=&v"(v) : "v"(p) : "memory");
    return v;
}
__device__ __forceinline__ void l2_store_u64(uint64_t* p, uint64_t v) {
    asm volatile("global_store_dwordx2 %0, %1, off sc0"
                 :: "v"(p), "v"(v) : "memory");
}

// ---------------------------------------------------------------------------
// init: zero h-record (both parities), fold biases, init ctrl + probe
// ---------------------------------------------------------------------------
__global__ __launch_bounds__(256) void init_k(uint64_t* __restrict__ hrec,
                                              const float* __restrict__ b_ih,
                                              const float* __restrict__ b_hh,
                                              float* __restrict__ bsum,
                                              uint32_t* __restrict__ ctrl,
                                              uint64_t* __restrict__ probe) {
    int i = blockIdx.x * 256 + threadIdx.x;   // grid 8x256 -> i in [0,2048)
    if (i < 1024) hrec[i] = 0ull;             // tag 0 == "h_{-1} ready", h = 0
    bsum[i] = b_ih[i] + b_hh[i];
    if (i < 16) ctrl[i] = (i == 8) ? 0xFFFFFFFFu : 0u;  // [8]=winner=-1
    else if (i < 16 + 512) probe[i - 16] = 0ull;
}

// ---------------------------------------------------------------------------
// C[M,N] = A[M,K] @ B[N,K]^T + bias[N]   (both operands K-contiguous)
// ---------------------------------------------------------------------------
__global__ __launch_bounds__(256) void gemm_abt(const float* __restrict__ A,
                                                const float* __restrict__ B,
                                                const float* __restrict__ bias,
                                                float* __restrict__ C,
                                                int N, int K) {
    __shared__ float As[16][68];
    __shared__ float Bs[16][68];
    const int tid = threadIdx.x;
    const int bm = blockIdx.x << 6, bn = blockIdx.y << 6;
    const int tx = tid & 15, ty = tid >> 4;
    const int lr = tid >> 2, lk = (tid & 3) << 2;
    float acc[4][4] = {};
    const float* Ap = A + (size_t)(bm + lr) * K + lk;
    const float* Bp = B + (size_t)(bn + lr) * K + lk;
    for (int kt = 0; kt < K; kt += 16) {
        float4 av = *(const float4*)(Ap + kt);
        float4 bv = *(const float4*)(Bp + kt);
        __syncthreads();
        As[lk + 0][lr] = av.x; As[lk + 1][lr] = av.y;
        As[lk + 2][lr] = av.z; As[lk + 3][lr] = av.w;
        Bs[lk + 0][lr] = bv.x; Bs[lk + 1][lr] = bv.y;
        Bs[lk + 2][lr] = bv.z; Bs[lk + 3][lr] = bv.w;
        __syncthreads();
#pragma unroll
        for (int kk = 0; kk < 16; ++kk) {
            float4 a4 = *(const float4*)&As[kk][ty << 2];
            float4 b4 = *(const float4*)&Bs[kk][tx << 2];
            acc[0][0] += a4.x * b4.x; acc[0][1] += a4.x * b4.y;
            acc[0][2] += a4.x * b4.z; acc[0][3] += a4.x * b4.w;
            acc[1][0] += a4.y * b4.x; acc[1][1] += a4.y * b4.y;
            acc[1][2] += a4.y * b4.z; acc[1][3] += a4.y * b4.w;
            acc[2][0] += a4.z * b4.x; acc[2][1] += a4.z * b4.y;
            acc[2][2] += a4.z * b4.z; acc[2][3] += a4.z * b4.w;
            acc[3][0] += a4.w * b4.x; acc[3][1] += a4.w * b4.y;
            acc[3][2] += a4.w * b4.z; acc[3][3] += a4.w * b4.w;
        }
    }
    const int col = bn + (tx << 2);
    float4 bv4 = *(const float4*)&bias[col];
#pragma unroll
    for (int i = 0; i < 4; ++i) {
        int row = bm + (ty << 2) + i;
        float4 o;
        o.x = acc[i][0] + bv4.x; o.y = acc[i][1] + bv4.y;
        o.z = acc[i][2] + bv4.z; o.w = acc[i][3] + bv4.w;
        *(float4*)&C[(size_t)row * N + col] = o;
    }
}

// ---------------------------------------------------------------------------
// Persistent LSTM scan. 256 blocks launched; 32 claim scan roles on the first
// XCD to fill 32 slots (pigeonhole: 256/8 XCDs guarantees a winner). A SOUND
// two-round sc0 coherence probe (round B rewrites lines round A cached -- a
// cross-XCD reader serves its stale cached copy and fails) decides between:
//   - L2 mode: sc0 spin/publish through the shared XCD L2 (D ~ 500 cyc), or
//   - fallback: byte-identical R2 agent-scope path (proven 22420 us).
// sc0 NEVER touches hrec unless the probe passed unanimously (a lingering
// dirty sc0 line evicted late could overwrite MALL with an ancient tag).
// Step body is R2-exact otherwise; xg is prefetched ONE STEP AHEAD so its
// ~900cy HBM latency drains before the spin instead of inside it (vmcnt FIFO).
// ---------------------------------------------------------------------------
__global__ __launch_bounds__(512, 2) void lstm_scan(const float* __restrict__ W_hh,
                                                    const float* __restrict__ xg,
                                                    float* __restrict__ hs,
                                                    uint64_t* __restrict__ hrec,
                                                    uint32_t* __restrict__ ctrl,
                                                    uint64_t* __restrict__ probe) {
    __shared__ __align__(16) float h_lds[512];
    __shared__ float part[2][512];
    __shared__ int role_sh;
    __shared__ int fail_sh;
    __shared__ int l2_sh;
    const int tid = threadIdx.x;
    const int wv = tid >> 6;          // wave 0..7 = k segment
    const int lane = tid & 63;        // row within block's 64 gate rows

    // ---- claim a scan role: first XCD to fill 32 slots wins ----
    if (tid == 0) {
        uint32_t xcd = ((uint32_t)__builtin_amdgcn_s_getreg(XCC_ID_ENC)) & 7u;
        uint32_t slot = __hip_atomic_fetch_add(&ctrl[xcd], 1u,
                            __ATOMIC_RELAXED, __HIP_MEMORY_SCOPE_AGENT);
        int role = -1;
        if (slot < (uint32_t)SCAN_BLOCKS) {
            if (slot == SCAN_BLOCKS - 1) {
                uint32_t exp = 0xFFFFFFFFu;
                __hip_atomic_compare_exchange_strong(&ctrl[8], &exp, xcd,
                    __ATOMIC_RELAXED, __ATOMIC_RELAXED, __HIP_MEMORY_SCOPE_AGENT);
            }
            uint32_t w; int g = 0;
            do {
                w = __hip_atomic_load(&ctrl[8], __ATOMIC_RELAXED,
                                      __HIP_MEMORY_SCOPE_AGENT);
            } while (w == 0xFFFFFFFFu && ++g < (1 << 22));
            if (w == xcd) role = (int)slot;
        }
        role_sh = role;
    }
    __syncthreads();
    const int j = role_sh;
    if (j < 0) return;                 // not a participant

    // participant barrier via monotonic agent-scope arrive counter
    auto pbar = [&](uint32_t epoch) {
        if (tid == 0) {
            asm volatile("s_waitcnt vmcnt(0)" ::: "memory");
            __hip_atomic_fetch_add(&ctrl[9], 1u, __ATOMIC_RELAXED,
                                   __HIP_MEMORY_SCOPE_AGENT);
            uint32_t tgt = (uint32_t)SCAN_BLOCKS * epoch, v; int g = 0;
            do {
                v = __hip_atomic_load(&ctrl[9], __ATOMIC_RELAXED,
                                      __HIP_MEMORY_SCOPE_AGENT);
            } while (v < tgt && ++g < (1 << 22));
        }
        __syncthreads();
    };

    // ---- SOUND two-round coherence probe (dedicated array, never reused) ----
    if (tid == 0) fail_sh = 0;
    __syncthreads();
    // round A: store magicA, read all (this CACHES the lines in reader L2s)
    if (wv == 0 && lane < 16)
        l2_store_u64(&probe[(j << 4) | lane],
                     ((uint64_t)(0xABC00000u | (uint32_t)j) << 32) | 0x5EEDull);
    pbar(1);
    {
        uint32_t want = 0xABC00000u | (uint32_t)(tid >> 4);
        uint64_t u; int g = 0;
        do { u = l2_load_u64(&probe[tid]); }
        while ((uint32_t)(u >> 32) != want && ++g < (1 << 15));
        if ((uint32_t)(u >> 32) != want) atomicOr(&fail_sh, 1);
    }
    pbar(2);   // everyone done reading A
    // round B: rewrite SAME lines; a cross-XCD reader re-serves cached magicA
    if (wv == 0 && lane < 16)
        l2_store_u64(&probe[(j << 4) | lane],
                     ((uint64_t)(0xDEF00000u | (uint32_t)j) << 32) | 0xBEEFull);
    pbar(3);
    {
        uint32_t want = 0xDEF00000u | (uint32_t)(tid >> 4);
        uint64_t u; int g = 0;
        do { u = l2_load_u64(&probe[tid]); }
        while ((uint32_t)(u >> 32) != want && ++g < (1 << 13));
        if ((uint32_t)(u >> 32) != want) atomicOr(&fail_sh, 1);
    }
    __syncthreads();
    if (tid == 0 && fail_sh)
        __hip_atomic_fetch_add(&ctrl[10], 1u, __ATOMIC_RELAXED,
                               __HIP_MEMORY_SCOPE_AGENT);
    pbar(4);
    if (tid == 0)
        l2_sh = (__hip_atomic_load(&ctrl[10], __ATOMIC_RELAXED,
                                   __HIP_MEMORY_SCOPE_AGENT) == 0u) ? 1 : 0;
    __syncthreads();
    const bool use_l2 = (l2_sh != 0);

    // ---- per-role setup (R2-exact body below) ----
    const int rowg = ((lane >> 4) << 9) | (j << 4) | (lane & 15);
    float4 w4[16];
    {
        const float4* wp = (const float4*)(W_hh + (size_t)rowg * HDIM + (wv << 6));
#pragma unroll
        for (int q = 0; q < 16; ++q) w4[q] = wp[q];
    }
    float xg_next = 0.f;
    if (wv == 0) xg_next = xg[rowg];   // xg(0) prefetch

    float c_reg = 0.f;   // valid on wave 0, lanes 0..15
    for (int t = 0; t < T_LEN; ++t) {
        float xgv = xg_next;   // use forces vmcnt drain BEFORE the spin

        // spin on my own 8B (h,tag) atom until tag == t
        uint64_t* src = hrec + ((t & 1) << 9) + tid;
        uint64_t a0;
        if (use_l2) {
            a0 = l2_load_u64(src);
            int g = 0;
            while ((uint32_t)(a0 >> 32) != (uint32_t)t && ++g < (1 << 18)) {
                __builtin_amdgcn_s_sleep(1);   // throttle shared-L2 flood
                a0 = l2_load_u64(src);
            }
        } else {
            a0 = __hip_atomic_load(src, __ATOMIC_RELAXED, __HIP_MEMORY_SCOPE_AGENT);
            uint64_t a1 = __hip_atomic_load(src, __ATOMIC_RELAXED, __HIP_MEMORY_SCOPE_AGENT);
            int g = 0;
            while ((uint32_t)(a0 >> 32) != (uint32_t)t && ++g < (1 << 18)) {
                a0 = a1;
                a1 = __hip_atomic_load(src, __ATOMIC_RELAXED, __HIP_MEMORY_SCOPE_AGENT);
            }
        }
        h_lds[tid] = __uint_as_float((uint32_t)a0);
        __builtin_amdgcn_wave_barrier();   // pin ds_write before own-segment reads

        // matvec: partial over my 64-k segment for my row (wave-local LDS)
        float ac0 = 0.f, ac1 = 0.f, ac2 = 0.f, ac3 = 0.f;
        const float* hp = h_lds + (wv << 6);
#pragma unroll
        for (int q = 0; q < 16; q += 4) {
            float4 h0 = *(const float4*)(hp + (q << 2));
            float4 h1 = *(const float4*)(hp + ((q + 1) << 2));
            float4 h2 = *(const float4*)(hp + ((q + 2) << 2));
            float4 h3 = *(const float4*)(hp + ((q + 3) << 2));
            ac0 += w4[q].x * h0.x + w4[q].y * h0.y + w4[q].z * h0.z + w4[q].w * h0.w;
            ac1 += w4[q + 1].x * h1.x + w4[q + 1].y * h1.y + w4[q + 1].z * h1.z + w4[q + 1].w * h1.w;
            ac2 += w4[q + 2].x * h2.x + w4[q + 2].y * h2.y + w4[q + 2].z * h2.z + w4[q + 2].w * h2.w;
            ac3 += w4[q + 3].x * h3.x + w4[q + 3].y * h3.y + w4[q + 3].z * h3.z + w4[q + 3].w * h3.w;
        }
        float v = (ac0 + ac1) + (ac2 + ac3);
        if (wv) part[t & 1][tid] = v;
        __syncthreads();    // the ONE barrier per step

        if (wv == 0) {
            float g = xgv + v;        // own seg-0 partial stays in-register
            const float* pp = part[t & 1];
#pragma unroll
            for (int ww = 1; ww < 8; ++ww) g += pp[(ww << 6) | lane];
            // rows 0..15 i(sig), 16..31 f(sig), 32..47 g(tanh), 48..63 o(sig)
            bool isg = (lane >= 32) && (lane < 48);
            float y = isg ? (g + g) : g;
            float s = 1.f / (1.f + __expf(-y));
            float a = isg ? (s + s - 1.f) : s;   // tanh(x) = 2*sig(2x)-1
            float fa = __shfl_down(a, 16);
            float ga = __shfl_down(a, 32);
            float oa = __shfl_down(a, 48);
            if (lane < 16) {
                c_reg = fa * c_reg + a * ga;
                float e2 = __expf(-2.f * c_reg);
                float hv = oa * (2.f / (1.f + e2) - 1.f);   // o * tanh(c)
                // publish FIRST, then record hs
                uint64_t pu = ((uint64_t)(uint32_t)(t + 1) << 32) |
                              (uint64_t)__float_as_uint(hv);
                uint64_t* dst = hrec + (((t + 1) & 1) << 9) + (j << 4) + lane;
                if (use_l2) l2_store_u64(dst, pu);
                else __hip_atomic_store(dst, pu, __ATOMIC_RELAXED,
                                        __HIP_MEMORY_SCOPE_AGENT);
                hs[(size_t)t * HDIM + (j << 4) + lane] = hv;
            }
            // prefetch next step's xg AFTER the tail (drained at next loop top)
            if (t + 1 < T_LEN) xg_next = xg[(size_t)(t + 1) * G4 + rowg];
        }
    }
}

// ---------------------------------------------------------------------------
// heads: per block, 64 t-rows. inter tile + transposed head weights in LDS.
// ---------------------------------------------------------------------------
__global__ __launch_bounds__(256) void heads_k(const float* __restrict__ inter,
                                               const float* __restrict__ fc1w,
                                               const float* __restrict__ fc1b,
                                               const float* __restrict__ fc2w,
                                               const float* __restrict__ fc2b,
                                               float* __restrict__ out) {
    __shared__ float it[64][128];   // 32 KB
    __shared__ float wt[128][56];   // 28 KB, transposed: [k][neuron]
    __shared__ float bl[56];
    const int tid = threadIdx.x;
    const int t0 = blockIdx.x << 6;
    for (int q = tid; q < 64 * 32; q += 256) {
        int r = q >> 5, c4 = q & 31;
        *(float4*)&it[r][c4 << 2] =
            *(const float4*)&inter[(size_t)(t0 + r) * 128 + (c4 << 2)];
    }
    for (int q = tid; q < 53 * 32; q += 256) {
        int r = q >> 5, c4 = q & 31;
        float4 v = (r < 16) ? ((const float4*)&fc1w[r * 128])[c4]
                            : ((const float4*)&fc2w[(r - 16) * 128])[c4];
        int k = c4 << 2;
        wt[k + 0][r] = v.x; wt[k + 1][r] = v.y; wt[k + 2][r] = v.z; wt[k + 3][r] = v.w;
    }
    if (tid < 53) bl[tid] = (tid < 16) ? fc1b[tid] : fc2b[tid - 16];
    __syncthreads();
    const int c = tid & 63, rg = tid >> 6;
    if (c < 53) {
        float b = bl[c];
        for (int rr = 0; rr < 16; ++rr) {
            int r = (rg << 4) + rr;
            float acc = b;
#pragma unroll 8
            for (int k = 0; k < 128; k += 4) {
                float4 iv = *(const float4*)&it[r][k];
                acc += iv.x * wt[k][c] + iv.y * wt[k + 1][c] +
                       iv.z * wt[k + 2][c] + iv.w * wt[k + 3][c];
            }
            acc = fminf(fmaxf(acc, 0.f), CLAMP_MAXV);
            int t = t0 + r;
            if (c < 16) out[(size_t)t * 16 + c] = acc;
            else        out[262144 + (size_t)t * 37 + (c - 16)] = acc;
        }
    }
}

// ---------------------------------------------------------------------------
extern "C" void kernel_launch(void* const* d_in, const int* in_sizes, int n_in,
                              void* d_out, int out_size, void* d_ws, size_t ws_size,
                              hipStream_t stream) {
    const float* x     = (const float*)d_in[0];
    const float* W_ih  = (const float*)d_in[1];
    const float* W_hh  = (const float*)d_in[2];
    const float* b_ih  = (const float*)d_in[3];
    const float* b_hh  = (const float*)d_in[4];
    const float* fc_w  = (const float*)d_in[5];
    const float* fc_b  = (const float*)d_in[6];
    const float* fc1_w = (const float*)d_in[7];
    const float* fc1_b = (const float*)d_in[8];
    const float* fc2_w = (const float*)d_in[9];
    const float* fc2_b = (const float*)d_in[10];

    if (ws_size < WS_NEED) return;   // visible failure rather than corruption

    char* ws = (char*)d_ws;
    float*    xg    = (float*)(ws + XG_OFF);
    float*    hs    = (float*)(ws + HS_OFF);
    float*    inter = (float*)(ws + INTER_OFF);
    uint64_t* hrec  = (uint64_t*)(ws + HREC_OFF);
    float*    bsum  = (float*)(ws + BSUM_OFF);
    uint32_t* ctrl  = (uint32_t*)(ws + INTER_OFF);        // 64 B, dead pre-scan
    uint64_t* probe = (uint64_t*)(ws + INTER_OFF + 64);   // 4 KB, dead pre-scan
    float*    out   = (float*)d_out;

    hipLaunchKernelGGL(init_k, dim3(8), dim3(256), 0, stream,
                       hrec, b_ih, b_hh, bsum, ctrl, probe);
    // x_gates = x @ W_ih^T + (b_ih + b_hh)   [16384 x 2048]
    hipLaunchKernelGGL(gemm_abt, dim3(256, 32), dim3(256), 0, stream,
                       x, W_ih, bsum, xg, 2048, 512);
    // sequential scan -> hs [16384 x 512]; 256 blocks, 32 claim roles
    hipLaunchKernelGGL(lstm_scan, dim3(256), dim3(512), 0, stream,
                       W_hh, xg, hs, hrec, ctrl, probe);
    // inter = hs @ fc_w^T + fc_b   [16384 x 128]
    hipLaunchKernelGGL(gemm_abt, dim3(256, 2), dim3(256), 0, stream,
                       hs, fc_w, fc_b, inter, 128, 512);
    // heads -> d_out
    hipLaunchKernelGGL(heads_k, dim3(256), dim3(256), 0, stream,
                       inter, fc1_w, fc1_b, fc2_w, fc2_b, out);
}

// Round 9
// 26016.086 us; speedup vs baseline: 1.0135x; 1.0135x over previous
//
#include <hip/hip_runtime.h>
#include <hip/hip_bf16.h>
#include <stdint.h>

#define T_LEN 16384
#define HDIM 512
#define G4 2048
#define CLAMP_MAXV 49688.0f

// workspace layout (bytes)
#define XG_OFF    0ull
#define HS_OFF    134217728ull   // 16384*2048*4
#define INTER_OFF 167772160ull   // + 16384*512*4  (ctrl+probe alias the first
                                 //  4.2KB of inter: dead until after the scan)
#define HREC_OFF  176160768ull   // + 16384*128*4
#define BSUM_OFF  176168960ull   // + 8192
#define WS_NEED   176177152ull

#define SCAN_BLOCKS 32
// s_getreg encoding: id=20 (HW_REG_XCC_ID, gfx940+), offset 0, size 32
#define XCC_ID_ENC (20 | (0 << 6) | ((32 - 1) << 11))

// sc0 (L1-bypass) 8B ops. Loads cache in the local XCD L2 -> only coherent
// when all participants share ONE physical L2. That property is VERIFIED by
// the two-round probe below; sc0 is never used on live data without a pass.
// R8 PROVED this path engages: FETCH_SIZE 414000 -> 130000 KB.
__device__ __forceinline__ uint64_t l2_load_u64(const uint64_t* p) {
    uint64_t v;
    asm volatile("global_load_dwordx2 %0, %1, off sc0\n\ts_waitcnt vmcnt(0)"
                 : "=&v"(v) : "v"(p) : "memory");
    return v;
}
__device__ __forceinline__ void l2_store_u64(uint64_t* p, uint64_t v) {
    asm volatile("global_store_dwordx2 %0, %1, off sc0"
                 :: "v"(p), "v"(v) : "memory");
}

// ---------------------------------------------------------------------------
// init: zero h-record (both parities), fold biases, init ctrl + probe
// ---------------------------------------------------------------------------
__global__ __launch_bounds__(256) void init_k(uint64_t* __restrict__ hrec,
                                              const float* __restrict__ b_ih,
                                              const float* __restrict__ b_hh,
                                              float* __restrict__ bsum,
                                              uint32_t* __restrict__ ctrl,
                                              uint64_t* __restrict__ probe) {
    int i = blockIdx.x * 256 + threadIdx.x;   // grid 8x256 -> i in [0,2048)
    if (i < 1024) hrec[i] = 0ull;             // tag 0 == "h_{-1} ready", h = 0
    bsum[i] = b_ih[i] + b_hh[i];
    if (i < 16) ctrl[i] = (i == 8) ? 0xFFFFFFFFu : 0u;  // [8]=winner=-1
    else if (i < 16 + 512) probe[i - 16] = 0ull;
}

// ---------------------------------------------------------------------------
// C[M,N] = A[M,K] @ B[N,K]^T + bias[N]   (both operands K-contiguous)
// ---------------------------------------------------------------------------
__global__ __launch_bounds__(256) void gemm_abt(const float* __restrict__ A,
                                                const float* __restrict__ B,
                                                const float* __restrict__ bias,
                                                float* __restrict__ C,
                                                int N, int K) {
    __shared__ float As[16][68];
    __shared__ float Bs[16][68];
    const int tid = threadIdx.x;
    const int bm = blockIdx.x << 6, bn = blockIdx.y << 6;
    const int tx = tid & 15, ty = tid >> 4;
    const int lr = tid >> 2, lk = (tid & 3) << 2;
    float acc[4][4] = {};
    const float* Ap = A + (size_t)(bm + lr) * K + lk;
    const float* Bp = B + (size_t)(bn + lr) * K + lk;
    for (int kt = 0; kt < K; kt += 16) {
        float4 av = *(const float4*)(Ap + kt);
        float4 bv = *(const float4*)(Bp + kt);
        __syncthreads();
        As[lk + 0][lr] = av.x; As[lk + 1][lr] = av.y;
        As[lk + 2][lr] = av.z; As[lk + 3][lr] = av.w;
        Bs[lk + 0][lr] = bv.x; Bs[lk + 1][lr] = bv.y;
        Bs[lk + 2][lr] = bv.z; Bs[lk + 3][lr] = bv.w;
        __syncthreads();
#pragma unroll
        for (int kk = 0; kk < 16; ++kk) {
            float4 a4 = *(const float4*)&As[kk][ty << 2];
            float4 b4 = *(const float4*)&Bs[kk][tx << 2];
            acc[0][0] += a4.x * b4.x; acc[0][1] += a4.x * b4.y;
            acc[0][2] += a4.x * b4.z; acc[0][3] += a4.x * b4.w;
            acc[1][0] += a4.y * b4.x; acc[1][1] += a4.y * b4.y;
            acc[1][2] += a4.y * b4.z; acc[1][3] += a4.y * b4.w;
            acc[2][0] += a4.z * b4.x; acc[2][1] += a4.z * b4.y;
            acc[2][2] += a4.z * b4.z; acc[2][3] += a4.z * b4.w;
            acc[3][0] += a4.w * b4.x; acc[3][1] += a4.w * b4.y;
            acc[3][2] += a4.w * b4.z; acc[3][3] += a4.w * b4.w;
        }
    }
    const int col = bn + (tx << 2);
    float4 bv4 = *(const float4*)&bias[col];
#pragma unroll
    for (int i = 0; i < 4; ++i) {
        int row = bm + (ty << 2) + i;
        float4 o;
        o.x = acc[i][0] + bv4.x; o.y = acc[i][1] + bv4.y;
        o.z = acc[i][2] + bv4.z; o.w = acc[i][3] + bv4.w;
        *(float4*)&C[(size_t)row * N + col] = o;
    }
}

// ---------------------------------------------------------------------------
// Persistent LSTM scan, single-XCD edition (R8 skeleton, L2 path proven by
// FETCH_SIZE 414->130 MB). ONE change vs R8:
//  - xg DEPTH-2 PREFETCH, ISSUED POST-SPIN. R8 issued xg(t+1) after the tail
//    and drained it at the next loop top -> ~500cy serial HBM stall in front
//    of every spin (ate the L2 win). Now: at spin exit of step t, issue
//    xg(t+2); consume xg(t) loaded two steps (~6000cy) ago -- always
//    complete, and the only outstanding xg load at any spin test was issued
//    a full step earlier (residual ~0).
// ---------------------------------------------------------------------------
__global__ __launch_bounds__(512, 2) void lstm_scan(const float* __restrict__ W_hh,
                                                    const float* __restrict__ xg,
                                                    float* __restrict__ hs,
                                                    uint64_t* __restrict__ hrec,
                                                    uint32_t* __restrict__ ctrl,
                                                    uint64_t* __restrict__ probe) {
    __shared__ __align__(16) float h_lds[512];
    __shared__ float part[2][512];
    __shared__ int role_sh;
    __shared__ int fail_sh;
    __shared__ int l2_sh;
    const int tid = threadIdx.x;
    const int wv = tid >> 6;          // wave 0..7 = k segment
    const int lane = tid & 63;        // row within block's 64 gate rows

    // ---- claim a scan role: first XCD to fill 32 slots wins ----
    if (tid == 0) {
        uint32_t xcd = ((uint32_t)__builtin_amdgcn_s_getreg(XCC_ID_ENC)) & 7u;
        uint32_t slot = __hip_atomic_fetch_add(&ctrl[xcd], 1u,
                            __ATOMIC_RELAXED, __HIP_MEMORY_SCOPE_AGENT);
        int role = -1;
        if (slot < (uint32_t)SCAN_BLOCKS) {
            if (slot == SCAN_BLOCKS - 1) {
                uint32_t exp = 0xFFFFFFFFu;
                __hip_atomic_compare_exchange_strong(&ctrl[8], &exp, xcd,
                    __ATOMIC_RELAXED, __ATOMIC_RELAXED, __HIP_MEMORY_SCOPE_AGENT);
            }
            uint32_t w; int g = 0;
            do {
                w = __hip_atomic_load(&ctrl[8], __ATOMIC_RELAXED,
                                      __HIP_MEMORY_SCOPE_AGENT);
            } while (w == 0xFFFFFFFFu && ++g < (1 << 22));
            if (w == xcd) role = (int)slot;
        }
        role_sh = role;
    }
    __syncthreads();
    const int j = role_sh;
    if (j < 0) return;                 // not a participant

    // participant barrier via monotonic agent-scope arrive counter
    auto pbar = [&](uint32_t epoch) {
        if (tid == 0) {
            asm volatile("s_waitcnt vmcnt(0)" ::: "memory");
            __hip_atomic_fetch_add(&ctrl[9], 1u, __ATOMIC_RELAXED,
                                   __HIP_MEMORY_SCOPE_AGENT);
            uint32_t tgt = (uint32_t)SCAN_BLOCKS * epoch, v; int g = 0;
            do {
                v = __hip_atomic_load(&ctrl[9], __ATOMIC_RELAXED,
                                      __HIP_MEMORY_SCOPE_AGENT);
            } while (v < tgt && ++g < (1 << 22));
        }
        __syncthreads();
    };

    // ---- SOUND two-round coherence probe (dedicated array, never reused) ----
    if (tid == 0) fail_sh = 0;
    __syncthreads();
    // round A: store magicA, read all (this CACHES the lines in reader L2s)
    if (wv == 0 && lane < 16)
        l2_store_u64(&probe[(j << 4) | lane],
                     ((uint64_t)(0xABC00000u | (uint32_t)j) << 32) | 0x5EEDull);
    pbar(1);
    {
        uint32_t want = 0xABC00000u | (uint32_t)(tid >> 4);
        uint64_t u; int g = 0;
        do { u = l2_load_u64(&probe[tid]); }
        while ((uint32_t)(u >> 32) != want && ++g < (1 << 15));
        if ((uint32_t)(u >> 32) != want) atomicOr(&fail_sh, 1);
    }
    pbar(2);   // everyone done reading A
    // round B: rewrite SAME lines; a cross-XCD reader re-serves cached magicA
    if (wv == 0 && lane < 16)
        l2_store_u64(&probe[(j << 4) | lane],
                     ((uint64_t)(0xDEF00000u | (uint32_t)j) << 32) | 0xBEEFull);
    pbar(3);
    {
        uint32_t want = 0xDEF00000u | (uint32_t)(tid >> 4);
        uint64_t u; int g = 0;
        do { u = l2_load_u64(&probe[tid]); }
        while ((uint32_t)(u >> 32) != want && ++g < (1 << 13));
        if ((uint32_t)(u >> 32) != want) atomicOr(&fail_sh, 1);
    }
    __syncthreads();
    if (tid == 0 && fail_sh)
        __hip_atomic_fetch_add(&ctrl[10], 1u, __ATOMIC_RELAXED,
                               __HIP_MEMORY_SCOPE_AGENT);
    pbar(4);
    if (tid == 0)
        l2_sh = (__hip_atomic_load(&ctrl[10], __ATOMIC_RELAXED,
                                   __HIP_MEMORY_SCOPE_AGENT) == 0u) ? 1 : 0;
    __syncthreads();
    const bool use_l2 = (l2_sh != 0);

    // ---- per-role setup ----
    const int rowg = ((lane >> 4) << 9) | (j << 4) | (lane & 15);
    float4 w4[16];
    {
        const float4* wp = (const float4*)(W_hh + (size_t)rowg * HDIM + (wv << 6));
#pragma unroll
        for (int q = 0; q < 16; ++q) w4[q] = wp[q];
    }
    // depth-2 xg pipeline (wave 0 only): xg_a = xg(t), xg_b = xg(t+1)
    float xg_a = 0.f, xg_b = 0.f;
    if (wv == 0) {
        xg_a = xg[rowg];
        xg_b = xg[(size_t)G4 + rowg];
    }

    float c_reg = 0.f;   // valid on wave 0, lanes 0..15
    for (int t = 0; t < T_LEN; ++t) {
        // spin on my own 8B (h,tag) atom until tag == t
        uint64_t* src = hrec + ((t & 1) << 9) + tid;
        uint64_t a0;
        if (use_l2) {
            a0 = l2_load_u64(src);
            int g = 0;
            while ((uint32_t)(a0 >> 32) != (uint32_t)t && ++g < (1 << 18)) {
                __builtin_amdgcn_s_sleep(1);   // throttle shared-L2 flood
                a0 = l2_load_u64(src);
            }
        } else {
            a0 = __hip_atomic_load(src, __ATOMIC_RELAXED, __HIP_MEMORY_SCOPE_AGENT);
            uint64_t a1 = __hip_atomic_load(src, __ATOMIC_RELAXED, __HIP_MEMORY_SCOPE_AGENT);
            int g = 0;
            while ((uint32_t)(a0 >> 32) != (uint32_t)t && ++g < (1 << 18)) {
                a0 = a1;
                a1 = __hip_atomic_load(src, __ATOMIC_RELAXED, __HIP_MEMORY_SCOPE_AGENT);
            }
        }
        // post-spin: issue xg(t+2) prefetch (completes long before its use;
        // at any spin test the only outstanding xg load is ~1 step old)
        float xg_n = 0.f;
        if (wv == 0) {
            int i2 = (t + 2 < T_LEN) ? (t + 2) : (T_LEN - 1);
            xg_n = xg[(size_t)i2 * G4 + rowg];
        }
        h_lds[tid] = __uint_as_float((uint32_t)a0);
        __builtin_amdgcn_wave_barrier();   // pin ds_write before own-segment reads

        // matvec: partial over my 64-k segment for my row (wave-local LDS)
        float ac0 = 0.f, ac1 = 0.f, ac2 = 0.f, ac3 = 0.f;
        const float* hp = h_lds + (wv << 6);
#pragma unroll
        for (int q = 0; q < 16; q += 4) {
            float4 h0 = *(const float4*)(hp + (q << 2));
            float4 h1 = *(const float4*)(hp + ((q + 1) << 2));
            float4 h2 = *(const float4*)(hp + ((q + 2) << 2));
            float4 h3 = *(const float4*)(hp + ((q + 3) << 2));
            ac0 += w4[q].x * h0.x + w4[q].y * h0.y + w4[q].z * h0.z + w4[q].w * h0.w;
            ac1 += w4[q + 1].x * h1.x + w4[q + 1].y * h1.y + w4[q + 1].z * h1.z + w4[q + 1].w * h1.w;
            ac2 += w4[q + 2].x * h2.x + w4[q + 2].y * h2.y + w4[q + 2].z * h2.z + w4[q + 2].w * h2.w;
            ac3 += w4[q + 3].x * h3.x + w4[q + 3].y * h3.y + w4[q + 3].z * h3.z + w4[q + 3].w * h3.w;
        }
        float v = (ac0 + ac1) + (ac2 + ac3);
        if (wv) part[t & 1][tid] = v;
        __syncthreads();    // the ONE barrier per step

        if (wv == 0) {
            float g = xg_a + v;       // xg(t): loaded 2 steps ago, complete
            const float* pp = part[t & 1];
#pragma unroll
            for (int ww = 1; ww < 8; ++ww) g += pp[(ww << 6) | lane];
            // rows 0..15 i(sig), 16..31 f(sig), 32..47 g(tanh), 48..63 o(sig)
            bool isg = (lane >= 32) && (lane < 48);
            float y = isg ? (g + g) : g;
            float s = 1.f / (1.f + __expf(-y));
            float a = isg ? (s + s - 1.f) : s;   // tanh(x) = 2*sig(2x)-1
            float fa = __shfl_down(a, 16);
            float ga = __shfl_down(a, 32);
            float oa = __shfl_down(a, 48);
            if (lane < 16) {
                c_reg = fa * c_reg + a * ga;
                float e2 = __expf(-2.f * c_reg);
                float hv = oa * (2.f / (1.f + e2) - 1.f);   // o * tanh(c)
                // publish FIRST, then record hs
                uint64_t pu = ((uint64_t)(uint32_t)(t + 1) << 32) |
                              (uint64_t)__float_as_uint(hv);
                uint64_t* dst = hrec + (((t + 1) & 1) << 9) + (j << 4) + lane;
                if (use_l2) l2_store_u64(dst, pu);
                else __hip_atomic_store(dst, pu, __ATOMIC_RELAXED,
                                        __HIP_MEMORY_SCOPE_AGENT);
                hs[(size_t)t * HDIM + (j << 4) + lane] = hv;
            }
        }
        xg_a = xg_b;   // rotate the depth-2 pipeline
        xg_b = xg_n;
    }
}

// ---------------------------------------------------------------------------
// heads: per block, 64 t-rows. inter tile + transposed head weights in LDS.
// ---------------------------------------------------------------------------
__global__ __launch_bounds__(256) void heads_k(const float* __restrict__ inter,
                                               const float* __restrict__ fc1w,
                                               const float* __restrict__ fc1b,
                                               const float* __restrict__ fc2w,
                                               const float* __restrict__ fc2b,
                                               float* __restrict__ out) {
    __shared__ float it[64][128];   // 32 KB
    __shared__ float wt[128][56];   // 28 KB, transposed: [k][neuron]
    __shared__ float bl[56];
    const int tid = threadIdx.x;
    const int t0 = blockIdx.x << 6;
    for (int q = tid; q < 64 * 32; q += 256) {
        int r = q >> 5, c4 = q & 31;
        *(float4*)&it[r][c4 << 2] =
            *(const float4*)&inter[(size_t)(t0 + r) * 128 + (c4 << 2)];
    }
    for (int q = tid; q < 53 * 32; q += 256) {
        int r = q >> 5, c4 = q & 31;
        float4 v = (r < 16) ? ((const float4*)&fc1w[r * 128])[c4]
                            : ((const float4*)&fc2w[(r - 16) * 128])[c4];
        int k = c4 << 2;
        wt[k + 0][r] = v.x; wt[k + 1][r] = v.y; wt[k + 2][r] = v.z; wt[k + 3][r] = v.w;
    }
    if (tid < 53) bl[tid] = (tid < 16) ? fc1b[tid] : fc2b[tid - 16];
    __syncthreads();
    const int c = tid & 63, rg = tid >> 6;
    if (c < 53) {
        float b = bl[c];
        for (int rr = 0; rr < 16; ++rr) {
            int r = (rg << 4) + rr;
            float acc = b;
#pragma unroll 8
            for (int k = 0; k < 128; k += 4) {
                float4 iv = *(const float4*)&it[r][k];
                acc += iv.x * wt[k][c] + iv.y * wt[k + 1][c] +
                       iv.z * wt[k + 2][c] + iv.w * wt[k + 3][c];
            }
            acc = fminf(fmaxf(acc, 0.f), CLAMP_MAXV);
            int t = t0 + r;
            if (c < 16) out[(size_t)t * 16 + c] = acc;
            else        out[262144 + (size_t)t * 37 + (c - 16)] = acc;
        }
    }
}

// ---------------------------------------------------------------------------
extern "C" void kernel_launch(void* const* d_in, const int* in_sizes, int n_in,
                              void* d_out, int out_size, void* d_ws, size_t ws_size,
                              hipStream_t stream) {
    const float* x     = (const float*)d_in[0];
    const float* W_ih  = (const float*)d_in[1];
    const float* W_hh  = (const float*)d_in[2];
    const float* b_ih  = (const float*)d_in[3];
    const float* b_hh  = (const float*)d_in[4];
    const float* fc_w  = (const float*)d_in[5];
    const float* fc_b  = (const float*)d_in[6];
    const float* fc1_w = (const float*)d_in[7];
    const float* fc1_b = (const float*)d_in[8];
    const float* fc2_w = (const float*)d_in[9];
    const float* fc2_b = (const float*)d_in[10];

    if (ws_size < WS_NEED) return;   // visible failure rather than corruption

    char* ws = (char*)d_ws;
    float*    xg    = (float*)(ws + XG_OFF);
    float*    hs    = (float*)(ws + HS_OFF);
    float*    inter = (float*)(ws + INTER_OFF);
    uint64_t* hrec  = (uint64_t*)(ws + HREC_OFF);
    float*    bsum  = (float*)(ws + BSUM_OFF);
    uint32_t* ctrl  = (uint32_t*)(ws + INTER_OFF);        // 64 B, dead pre-scan
    uint64_t* probe = (uint64_t*)(ws + INTER_OFF + 64);   // 4 KB, dead pre-scan
    float*    out   = (float*)d_out;

    hipLaunchKernelGGL(init_k, dim3(8), dim3(256), 0, stream,
                       hrec, b_ih, b_hh, bsum, ctrl, probe);
    // x_gates = x @ W_ih^T + (b_ih + b_hh)   [16384 x 2048]
    hipLaunchKernelGGL(gemm_abt, dim3(256, 32), dim3(256), 0, stream,
                       x, W_ih, bsum, xg, 2048, 512);
    // sequential scan -> hs [16384 x 512]; 256 blocks, 32 claim roles
    hipLaunchKernelGGL(lstm_scan, dim3(256), dim3(512), 0, stream,
                       W_hh, xg, hs, hrec, ctrl, probe);
    // inter = hs @ fc_w^T + fc_b   [16384 x 128]
    hipLaunchKernelGGL(gemm_abt, dim3(256, 2), dim3(256), 0, stream,
                       hs, fc_w, fc_b, inter, 128, 512);
    // heads -> d_out
    hipLaunchKernelGGL(heads_k, dim3(256), dim3(256), 0, stream,
                       inter, fc1_w, fc1_b, fc2_w, fc2_b, out);
}